// Round 6
// baseline (859.914 us; speedup 1.0000x reference)
//
#include <hip/hip_runtime.h>
#include <float.h>

// Problem constants (match reference)
constexpr int H = 1024, W = 1024, C = 128, N_ITER = 8;
constexpr int TPB    = 256;       // threads per block (4 waves)
constexpr int NBLK   = 256;       // persistent blocks; <= worst-case capacity (1024) -> no deadlock
constexpr int SLOTS  = 2 * C;     // 256 accumulator slots
constexpr int CNT_SH = 16;        // sharded arrival counters (depth 16 per address)
constexpr int GROUPS = 4;         // 4 row-groups x 4 px/thread = 16 px/thread (64x64 tile)

// Round-5 lesson: hipLaunchCooperativeKernel silently failed (all-zero out, no
// hang). Same fusion, plain launch: 256 blocks is co-resident BY CAPACITY
// (launch_bounds(256,4) -> >=4 blocks/CU -> capacity 1024 >= 256), so a
// hand-rolled global barrier cannot deadlock. Cross-XCD visibility uses ONLY
// explicit agent-scope atomic load/store/fetch_add + __threadfence (G16-safe;
// no reliance on fp-atomic scope semantics).
//
// Per iteration (math identical to rounds 1-4, absmax 0.0):
//  phase 0: clusters from reduced[it-1] (workers gate on epoch flag).
//  phase 1: exact 64x64-tile triangle prune (keep iff dcen <= dmin + 2r + 1,
//           r = 31.5*sqrt(2), threshold 91.0 > 90.096) + exact coincident-
//           cluster dedup (branch-free scan — round-4's early-break serialized).
//  phase 2: argmin over ~2-16 candidates; heatmap float4s loaded ONCE before
//           the iteration loop and held in registers (16 floats).
//  publish: block-private partial row (agent atomic stores, NO contention),
//           fence, sharded release-counter. Block 0: acquire-poll counters,
//           reduce 256x256 partials, publish reduced[] + release flag.
__device__ __forceinline__ float agent_load_f(const float* p) {
    return __hip_atomic_load(p, __ATOMIC_RELAXED, __HIP_MEMORY_SCOPE_AGENT);
}
__device__ __forceinline__ void agent_store_f(float* p, float v) {
    __hip_atomic_store(p, v, __ATOMIC_RELAXED, __HIP_MEMORY_SCOPE_AGENT);
}

__global__ __launch_bounds__(TPB, 4) void kmeans_persist(
    const float* __restrict__ clusters0,  // [SLOTS] input clusters
    const float* __restrict__ heatmap,    // [H,W]
    float* __restrict__ P,                // [N_ITER][NBLK][SLOTS] block-private partials
    float* __restrict__ reduced,          // [N_ITER][SLOTS]
    unsigned* __restrict__ cnt,           // [N_ITER][CNT_SH], zeroed each launch
    unsigned* __restrict__ flag,          // epoch, zeroed each launch
    float* __restrict__ out)              // [SLOTS]
{
    __shared__ float2 cls[C];
    __shared__ float2 cand[C];
    __shared__ int    candIdx[C];
    __shared__ float  waveMin[2];
    __shared__ int    waveCnt[2];
    __shared__ float  acc[SLOTS];         // SLOTS == 256 == TPB

    const int tid = threadIdx.x;
    const int blk = blockIdx.x;
    const int tr  = (blk >> 4) * 64;      // 16x16 grid of 64x64 tiles
    const int tc  = (blk & 15) * 64;

    // ---- persistent per-thread pixel state (held for all 8 iterations) ----
    const int   rIn = tid >> 4;           // 0..15
    const int   c0  = tc + (tid & 15) * 4;
    const float cf0 = (float)c0;
    float hval[GROUPS][4];
    float frg[GROUPS];
#pragma unroll
    for (int g = 0; g < GROUPS; ++g) {
        const int row = tr + rIn + 16 * g;
        const float4 h4 = *(const float4*)(heatmap + (size_t)row * W + c0);
        hval[g][0] = h4.x; hval[g][1] = h4.y; hval[g][2] = h4.z; hval[g][3] = h4.w;
        frg[g] = (float)row;
    }
    const float ctrR = (float)tr + 31.5f;
    const float ctrC = (float)tc + 31.5f;

    float myS = 0.0f;                     // block 0: my reduced value for slot tid

    for (int it = 0; it < N_ITER; ++it) {
        // ---- phase 0: current cluster coords into LDS ----
        float coord;
        if (it == 0) {
            coord = clusters0[tid];
        } else if (blk == 0) {
            coord = myS;                  // block 0 computed the reduction itself
        } else {
            if (tid == 0) {
                while (__hip_atomic_load(flag, __ATOMIC_ACQUIRE,
                                         __HIP_MEMORY_SCOPE_AGENT) < (unsigned)it)
                    __builtin_amdgcn_s_sleep(1);
            }
            __syncthreads();              // extends tid0's acquire to the block
            coord = agent_load_f(&reduced[(size_t)(it - 1) * SLOTS + tid]);
        }
        ((float*)cls)[tid] = coord;
        acc[tid] = 0.0f;
        __syncthreads();

        // ---- phase 1a: distance from tile center, per-wave min ----
        float dcen = 0.0f;
        if (tid < C) {
            const float2 cl = cls[tid];
            const float dxr = cl.x - ctrR;
            const float dyc = cl.y - ctrC;
            dcen = sqrtf(dxr * dxr + dyc * dyc);
            float m = dcen;
#pragma unroll
            for (int off = 32; off > 0; off >>= 1)
                m = fminf(m, __shfl_xor(m, off));
            if ((tid & 63) == 0) waveMin[tid >> 6] = m;
        }
        __syncthreads();

        // ---- phase 1b: prune + branch-free dedup + ballot compaction ----
        bool keep = false;
        int  pre  = 0;
        if (tid < C) {
            // 2*r + 1 = 2*31.5*sqrt(2) + 1 = 90.0955; 91.0 adds exact-safe slack
            const float thr = fminf(waveMin[0], waveMin[1]) + 91.0f;
            const float2 me = cls[tid];
            unsigned dup = 0u;
#pragma unroll 8
            for (int j = 0; j < C; ++j) {  // no early break: pipelined LDS broadcasts
                const float2 o = cls[j];
                dup |= (unsigned)(j < tid) & (unsigned)(o.x == me.x)
                                           & (unsigned)(o.y == me.y);
            }
            keep = (dcen <= thr) && !dup;
            const unsigned long long mask = __ballot(keep);
            const int lane = tid & 63;
            pre = __popcll(mask & ((1ull << lane) - 1ull));
            if (lane == 0) waveCnt[tid >> 6] = __popcll(mask);
        }
        __syncthreads();
        if (keep) {
            const int pos = pre + ((tid >= 64) ? waveCnt[0] : 0);
            cand[pos]    = cls[tid];
            candIdx[pos] = tid;
        }
        __syncthreads();

        const int nCand = waveCnt[0] + waveCnt[1];   // >= 1 (nearest always kept)

        // ---- phase 2 + epilogue, per row-group (keeps live VGPRs low) ----
#pragma unroll
        for (int g = 0; g < GROUPS; ++g) {
            const float fr = frg[g];
            float best[4];
            int   bi[4];
#pragma unroll
            for (int p = 0; p < 4; ++p) { best[p] = FLT_MAX; bi[p] = 0; }

            for (int k = 0; k < nCand; ++k) {
                const float2 cl = cand[k];            // LDS broadcast
                const int    ci = candIdx[k];
                const float  dx  = fr - cl.x;
                const float  dx2 = dx * dx;           // row-constant, reused x4
#pragma unroll
                for (int p = 0; p < 4; ++p) {
                    const float dy  = (cf0 + (float)p) - cl.y;
                    const float d2  = fmaf(dy, dy, dx2);
                    const float key = fmaxf(d2, 1.0f);  // clamp before compare
                    const bool  lt  = key < best[p];    // strict <: first-index ties
                    bi[p]   = lt ? ci  : bi[p];
                    best[p] = lt ? key : best[p];
                }
            }

#pragma unroll
            for (int p = 0; p < 4; ++p) {
                const float bd  = fmaxf(1.0f, sqrtf(best[p]));  // = max(1,sqrt(d2))
                const float wgt = hval[g][p] / bd;
                float v0 = fr * wgt;
                float v1 = (cf0 + (float)p) * wgt;
                const int b0 = __shfl(bi[p], 0);
                if (__ballot(bi[p] == b0) == 0xFFFFFFFFFFFFFFFFull) {
#pragma unroll
                    for (int off = 32; off > 0; off >>= 1) {
                        v0 += __shfl_xor(v0, off);
                        v1 += __shfl_xor(v1, off);
                    }
                    if ((tid & 63) == 0) {
                        unsafeAtomicAdd(&acc[2 * b0 + 0], v0);
                        unsafeAtomicAdd(&acc[2 * b0 + 1], v1);
                    }
                } else {
                    unsafeAtomicAdd(&acc[2 * bi[p] + 0], v0);
                    unsafeAtomicAdd(&acc[2 * bi[p] + 1], v1);
                }
            }
        }
        __syncthreads();

        // ---- publish block-private partials; release sharded arrival counter ----
        agent_store_f(&P[((size_t)it * NBLK + blk) * SLOTS + tid], acc[tid]);
        __threadfence();                  // own stores globally visible pre-barrier
        __syncthreads();
        if (tid == 0)
            __hip_atomic_fetch_add(&cnt[it * CNT_SH + (blk & (CNT_SH - 1))], 1u,
                                   __ATOMIC_RELEASE, __HIP_MEMORY_SCOPE_AGENT);

        // ---- block 0: wait for all arrivals, reduce, publish ----
        if (blk == 0) {
            if (tid < 64) {               // wave 0 polls the 16 counter shards
                const unsigned* cb = cnt + it * CNT_SH;
                int total = 0;
                do {
                    unsigned v = (tid < CNT_SH)
                        ? __hip_atomic_load(&cb[tid], __ATOMIC_ACQUIRE,
                                            __HIP_MEMORY_SCOPE_AGENT) : 0u;
                    int s = (int)v;
#pragma unroll
                    for (int off = 32; off > 0; off >>= 1) s += __shfl_xor(s, off);
                    total = s;
                    if (total < NBLK) __builtin_amdgcn_s_sleep(1);
                } while (total < NBLK);
            }
            __syncthreads();

            float s = 0.0f;
            const float* pb = P + (size_t)it * NBLK * SLOTS + tid;
#pragma unroll 8
            for (int b = 0; b < NBLK; ++b) s += agent_load_f(pb + (size_t)b * SLOTS);

            if (it == N_ITER - 1) {
                out[tid] = s;             // plain store; kernel-end flush
            } else {
                agent_store_f(&reduced[(size_t)it * SLOTS + tid], s);
                __threadfence();
                __syncthreads();
                if (tid == 0)
                    __hip_atomic_store(flag, (unsigned)(it + 1),
                                       __ATOMIC_RELEASE, __HIP_MEMORY_SCOPE_AGENT);
                myS = s;
            }
        }
    }
}

extern "C" void kernel_launch(void* const* d_in, const int* in_sizes, int n_in,
                              void* d_out, int out_size, void* d_ws, size_t ws_size,
                              hipStream_t stream) {
    const float* clusters = (const float*)d_in[0];  // [C,2] = 256 floats
    const float* heatmap  = (const float*)d_in[1];  // [H,W] = 1M floats
    float* out = (float*)d_out;                     // [C,2] = 256 floats

    // d_ws layout (ws is ~256 MB; we use ~2.1 MB):
    float*    P       = (float*)d_ws;                         // 8*256*256 f = 2 MB
    float*    reduced = P + (size_t)N_ITER * NBLK * SLOTS;    // 8*256 f = 8 KB
    unsigned* cnt     = (unsigned*)(reduced + N_ITER * SLOTS);// 8*16 u32 = 512 B
    unsigned* flag    = cnt + N_ITER * CNT_SH;                // 1 u32

    // Only control state needs zeroing (P/reduced are written-before-read,
    // gated by the counters/flag). Harness re-poisons d_ws before every launch.
    hipMemsetAsync(cnt, 0, (N_ITER * CNT_SH + 1) * sizeof(unsigned), stream);

    kmeans_persist<<<NBLK, TPB, 0, stream>>>(clusters, heatmap, P, reduced,
                                             cnt, flag, out);
}

// Round 7
// 324.300 us; speedup vs baseline: 2.6516x; 2.6516x over previous
//
#include <hip/hip_runtime.h>
#include <float.h>

// Problem constants (match reference)
constexpr int H = 1024, W = 1024, C = 128, N_ITER = 8;
constexpr int TPB    = 256;       // threads per block (4 waves)
constexpr int NBLK   = 128;       // 16x8 grid of 64x128 tiles; <= 256 CUs -> co-resident
constexpr int SLOTS  = 2 * C;     // 256 accumulator slots
constexpr int CNT_SH = 16;        // sharded arrival counters
constexpr int GROUPS = 8;         // 8 row-groups x 4 cols = 32 px/thread

// Round-6 lesson: the fused persistent kernel was correct but the transport was
// per-element agent-scope ATOMIC loads (serialized, uncached, ~500+cyc each) and
// a two-hop block0-reduce->flag->broadcast chain -> ~100us/iter. Round 7 keeps
// the fusion, rebuilds transport as the standard fence pattern (same as ROCm's
// own grid.sync): plain stores -> __syncthreads (vmcnt drain) -> RELEASE
// fetch_add on sharded counter; readers poll RELAXED, one ACQUIRE agent fence
// (buffer_inv), then plain coalesced loads. Single hop: EVERY block reduces the
// 128 partial rows itself (128KB/block, ~16MB/iter aggregate at LLC BW).
//
// Algorithm per iteration (identical math to rounds 1-4, absmax 0.0):
//   phase 1: exact triangle prune (keep iff dcen <= dmin + 2r + 1; 64x128 tile,
//            r = sqrt(31.5^2+63.5^2) = 70.88, threshold 143.5 > 142.77) +
//            exact coincident-cluster dedup (strict-'<' argmin -> only lowest
//            index of a coincident set can win; iters 3+ have ~127 clusters at
//            exactly (0,0) from empty segment_sum segments).
//   phase 2: argmin over surviving candidates; heatmap held in registers for
//            all 8 iterations (32 floats/thread).
//   epilogue: wave-uniform fast path (butterfly + 1 LDS atomic) else per-lane
//            LDS atomics; block-private partial row -> plain stores.
__global__ __launch_bounds__(TPB, 4) void kmeans_persist(
    const float* __restrict__ clusters0,  // [SLOTS] input clusters
    const float* __restrict__ heatmap,    // [H,W]
    float* __restrict__ P,                // [N_ITER][NBLK][SLOTS] block-private partials
    unsigned* __restrict__ cnt,           // [N_ITER][CNT_SH], zeroed each launch
    float* __restrict__ out)              // [SLOTS]
{
    __shared__ float2 cls[C];
    __shared__ float2 cand[C];
    __shared__ int    candIdx[C];
    __shared__ float  waveMin[2];
    __shared__ int    waveCnt[2];
    __shared__ float  acc[SLOTS];         // SLOTS == 256 == TPB

    const int tid = threadIdx.x;
    const int blk = blockIdx.x;
    const int tr  = (blk >> 3) * 64;      // 16 tile-rows
    const int tc  = (blk & 7) * 128;      // 8 tile-cols

    // ---- persistent per-thread pixel state (held for all 8 iterations) ----
    const int   rIn = tid >> 5;           // 0..7
    const int   c0  = tc + (tid & 31) * 4;
    const float cf0 = (float)c0;
    float hval[GROUPS][4];
    float frg[GROUPS];
#pragma unroll
    for (int g = 0; g < GROUPS; ++g) {
        const int row = tr + rIn + 8 * g;
        const float4 h4 = *(const float4*)(heatmap + (size_t)row * W + c0);
        hval[g][0] = h4.x; hval[g][1] = h4.y; hval[g][2] = h4.z; hval[g][3] = h4.w;
        frg[g] = (float)row;
    }
    const float ctrR = (float)tr + 31.5f;
    const float ctrC = (float)tc + 63.5f;

    float coord = clusters0[tid];         // iter-0 cluster coords

    for (int it = 0; it < N_ITER; ++it) {
        // ---- load clusters into LDS ----
        ((float*)cls)[tid] = coord;
        acc[tid] = 0.0f;
        __syncthreads();

        // ---- phase 1a: distance from tile center, per-wave min ----
        float dcen = 0.0f;
        if (tid < C) {
            const float2 cl = cls[tid];
            const float dxr = cl.x - ctrR;
            const float dyc = cl.y - ctrC;
            dcen = sqrtf(dxr * dxr + dyc * dyc);
            float m = dcen;
#pragma unroll
            for (int off = 32; off > 0; off >>= 1)
                m = fminf(m, __shfl_xor(m, off));
            if ((tid & 63) == 0) waveMin[tid >> 6] = m;
        }
        __syncthreads();

        // ---- phase 1b: prune + branch-free dedup + ballot compaction ----
        bool keep = false;
        int  pre  = 0;
        if (tid < C) {
            // 2*r + 1 = 2*70.8837 + 1 = 142.77; 143.5 adds exact-safe slack
            const float thr = fminf(waveMin[0], waveMin[1]) + 143.5f;
            const float2 me = cls[tid];
            unsigned dup = 0u;
#pragma unroll 8
            for (int j = 0; j < C; ++j) {  // LDS broadcasts, no early break
                const float2 o = cls[j];
                dup |= (unsigned)(j < tid) & (unsigned)(o.x == me.x)
                                           & (unsigned)(o.y == me.y);
            }
            keep = (dcen <= thr) && !dup;
            const unsigned long long mask = __ballot(keep);
            const int lane = tid & 63;
            pre = __popcll(mask & ((1ull << lane) - 1ull));
            if (lane == 0) waveCnt[tid >> 6] = __popcll(mask);
        }
        __syncthreads();
        if (keep) {
            const int pos = pre + ((tid >= 64) ? waveCnt[0] : 0);
            cand[pos]    = cls[tid];
            candIdx[pos] = tid;
        }
        __syncthreads();

        const int nCand = waveCnt[0] + waveCnt[1];   // >= 1 (nearest always kept)

        // ---- phase 2 + epilogue, per row-group ----
#pragma unroll
        for (int g = 0; g < GROUPS; ++g) {
            const float fr = frg[g];
            float best[4];
            int   bi[4];
#pragma unroll
            for (int p = 0; p < 4; ++p) { best[p] = FLT_MAX; bi[p] = 0; }

            for (int k = 0; k < nCand; ++k) {
                const float2 cl = cand[k];            // LDS broadcast
                const int    ci = candIdx[k];
                const float  dx  = fr - cl.x;
                const float  dx2 = dx * dx;           // row-constant, reused x4
#pragma unroll
                for (int p = 0; p < 4; ++p) {
                    const float dy  = (cf0 + (float)p) - cl.y;
                    const float d2  = fmaf(dy, dy, dx2);
                    const float key = fmaxf(d2, 1.0f);  // clamp before compare
                    const bool  lt  = key < best[p];    // strict <: first-index ties
                    bi[p]   = lt ? ci  : bi[p];
                    best[p] = lt ? key : best[p];
                }
            }

#pragma unroll
            for (int p = 0; p < 4; ++p) {
                const float bd  = fmaxf(1.0f, sqrtf(best[p]));  // = max(1,sqrt(d2))
                const float wgt = hval[g][p] / bd;
                float v0 = fr * wgt;
                float v1 = (cf0 + (float)p) * wgt;
                const int b0 = __shfl(bi[p], 0);
                if (__ballot(bi[p] == b0) == 0xFFFFFFFFFFFFFFFFull) {
#pragma unroll
                    for (int off = 32; off > 0; off >>= 1) {
                        v0 += __shfl_xor(v0, off);
                        v1 += __shfl_xor(v1, off);
                    }
                    if ((tid & 63) == 0) {
                        unsafeAtomicAdd(&acc[2 * b0 + 0], v0);
                        unsafeAtomicAdd(&acc[2 * b0 + 1], v1);
                    }
                } else {
                    unsafeAtomicAdd(&acc[2 * bi[p] + 0], v0);
                    unsafeAtomicAdd(&acc[2 * bi[p] + 1], v1);
                }
            }
        }
        __syncthreads();

        // ---- publish: plain store of this block's private partial row ----
        P[((size_t)it * NBLK + blk) * SLOTS + tid] = acc[tid];
        __syncthreads();                  // drains vmcnt for ALL waves' stores
        if (tid == 0)                     // release: wbl2 + visible counter bump
            __hip_atomic_fetch_add(&cnt[it * CNT_SH + (blk & (CNT_SH - 1))], 1u,
                                   __ATOMIC_RELEASE, __HIP_MEMORY_SCOPE_AGENT);

        if (it == N_ITER - 1) {
            // workers exit; block 0 reduces into d_out below
            break;
        }

        // ---- arrival barrier: wave 0 polls shard counters (relaxed) ----
        if (tid < 64) {
            const unsigned* cb = cnt + it * CNT_SH;
            int total = 0;
            do {
                unsigned v = (tid < CNT_SH)
                    ? __hip_atomic_load(&cb[tid], __ATOMIC_RELAXED,
                                        __HIP_MEMORY_SCOPE_AGENT) : 0u;
                int s = (int)v;
#pragma unroll
                for (int off = 32; off > 0; off >>= 1) s += __shfl_xor(s, off);
                total = s;
                if (total < NBLK) __builtin_amdgcn_s_sleep(2);
            } while (total < NBLK);
        }
        __syncthreads();
        // one acquire fence (buffer_inv): everything released before the
        // counters reached NBLK is now visible to plain loads
        __builtin_amdgcn_fence(__ATOMIC_ACQUIRE, "agent");

        // ---- every block reduces the partials itself (coalesced plain loads) ----
        float s = 0.0f;
        const float* pb = P + (size_t)it * NBLK * SLOTS + tid;
#pragma unroll 8
        for (int b = 0; b < NBLK; ++b) s += pb[(size_t)b * SLOTS];
        coord = s;
    }

    // ---- finalize: block 0 reduces the last iteration into d_out ----
    if (blk == 0) {
        if (tid < 64) {
            const unsigned* cb = cnt + (N_ITER - 1) * CNT_SH;
            int total = 0;
            do {
                unsigned v = (tid < CNT_SH)
                    ? __hip_atomic_load(&cb[tid], __ATOMIC_RELAXED,
                                        __HIP_MEMORY_SCOPE_AGENT) : 0u;
                int s = (int)v;
#pragma unroll
                for (int off = 32; off > 0; off >>= 1) s += __shfl_xor(s, off);
                total = s;
                if (total < NBLK) __builtin_amdgcn_s_sleep(2);
            } while (total < NBLK);
        }
        __syncthreads();
        __builtin_amdgcn_fence(__ATOMIC_ACQUIRE, "agent");

        float s = 0.0f;
        const float* pb = P + (size_t)(N_ITER - 1) * NBLK * SLOTS + tid;
#pragma unroll 8
        for (int b = 0; b < NBLK; ++b) s += pb[(size_t)b * SLOTS];
        out[tid] = s;
    }
}

extern "C" void kernel_launch(void* const* d_in, const int* in_sizes, int n_in,
                              void* d_out, int out_size, void* d_ws, size_t ws_size,
                              hipStream_t stream) {
    const float* clusters = (const float*)d_in[0];  // [C,2] = 256 floats
    const float* heatmap  = (const float*)d_in[1];  // [H,W] = 1M floats
    float* out = (float*)d_out;                     // [C,2] = 256 floats

    // d_ws layout: P = 8*128*256 floats (1 MB), then counters (512 B)
    float*    P   = (float*)d_ws;
    unsigned* cnt = (unsigned*)(P + (size_t)N_ITER * NBLK * SLOTS);

    // only the counters need zeroing; P rows are fully written before any read
    hipMemsetAsync(cnt, 0, N_ITER * CNT_SH * sizeof(unsigned), stream);

    kmeans_persist<<<NBLK, TPB, 0, stream>>>(clusters, heatmap, P, cnt, out);
}

// Round 8
// 246.349 us; speedup vs baseline: 3.4906x; 1.3164x over previous
//
#include <hip/hip_runtime.h>
#include <float.h>

// Problem constants (match reference)
constexpr int H = 1024, W = 1024, C = 128, N_ITER = 8;
constexpr int TPB    = 256;       // threads per block (4 waves)
constexpr int NBLK   = 128;       // 16x8 grid of 64x128 tiles; co-resident by capacity
constexpr int SLOTS  = 2 * C;     // 256 accumulator slots
constexpr int ASH    = 4;         // accumulator shards (depth <= NBLK/ASH = 32)
constexpr int CNT_SH = 16;        // sharded arrival counters
constexpr int GROUPS = 8;         // 8 row-groups x 4 cols = 32 px/thread

// Round-6 lesson: per-element agent ATOMIC loads serialize (~100us/iter).
// Round-7 lesson: plain-store transport forces release-wbL2 + acquire-inv L2
// walks per block per iter (~34us/iter). Round 8: ALL cross-block data goes
// through the device coherence point natively:
//   writers:  unsafeAtomicAdd (device-coherent fp32 RMW, proven cheap in r4)
//             of the few NONZERO LDS slots into A[it][blk&3][slot];
//             __syncthreads (vmcnt drain => RMWs complete at LLC);
//             relaxed fetch_add on sharded arrival counter (also at LLC).
//   readers:  poll counters (relaxed atomic loads), then read the new cluster
//             coords with FOUR relaxed atomic loads/thread (shard sum).
// No fences, no wbL2, no buffer_inv, no bulk partial-reduce.
//
// Algorithm per iteration (identical math to rounds 1-4, absmax 0.0):
//   phase 1: exact triangle prune (keep iff dcen <= dmin + 2r + 1; 64x128
//            tile, r = 70.8837, threshold 143.5 > 142.77) + exact coincident-
//            cluster dedup (strict-'<' argmin -> only lowest index of a
//            coincident set can win; iters 3+ have ~127 clusters at exactly
//            (0,0) from empty segment_sum segments).
//   phase 2: argmin over surviving candidates; heatmap held in registers for
//            all 8 iterations (32 floats/thread).
//   epilogue: wave-uniform fast path (butterfly + 1 LDS atomic) else per-lane
//            LDS atomics.
__global__ __launch_bounds__(TPB, 4) void kmeans_persist(
    const float* __restrict__ clusters0,  // [SLOTS] input clusters
    const float* __restrict__ heatmap,    // [H,W]
    float* __restrict__ A,                // [N_ITER][ASH][SLOTS], zeroed each launch
    unsigned* __restrict__ cnt,           // [N_ITER][CNT_SH], zeroed each launch
    float* __restrict__ out)              // [SLOTS]
{
    __shared__ float2 cls[C];
    __shared__ float2 cand[C];
    __shared__ int    candIdx[C];
    __shared__ float  waveMin[2];
    __shared__ int    waveCnt[2];
    __shared__ float  acc[SLOTS];         // SLOTS == 256 == TPB

    const int tid = threadIdx.x;
    const int blk = blockIdx.x;
    const int tr  = (blk >> 3) * 64;      // 16 tile-rows
    const int tc  = (blk & 7) * 128;      // 8 tile-cols

    // ---- persistent per-thread pixel state (held for all 8 iterations) ----
    const int   rIn = tid >> 5;           // 0..7
    const int   c0  = tc + (tid & 31) * 4;
    const float cf0 = (float)c0;
    float hval[GROUPS][4];
    float frg[GROUPS];
#pragma unroll
    for (int g = 0; g < GROUPS; ++g) {
        const int row = tr + rIn + 8 * g;
        const float4 h4 = *(const float4*)(heatmap + (size_t)row * W + c0);
        hval[g][0] = h4.x; hval[g][1] = h4.y; hval[g][2] = h4.z; hval[g][3] = h4.w;
        frg[g] = (float)row;
    }
    const float ctrR = (float)tr + 31.5f;
    const float ctrC = (float)tc + 63.5f;

    float coord = clusters0[tid];         // iter-0 cluster coords

    for (int it = 0; it < N_ITER; ++it) {
        // ---- load clusters into LDS ----
        ((float*)cls)[tid] = coord;
        acc[tid] = 0.0f;
        __syncthreads();

        // ---- phase 1a: distance from tile center, per-wave min ----
        float dcen = 0.0f;
        if (tid < C) {
            const float2 cl = cls[tid];
            const float dxr = cl.x - ctrR;
            const float dyc = cl.y - ctrC;
            dcen = sqrtf(dxr * dxr + dyc * dyc);
            float m = dcen;
#pragma unroll
            for (int off = 32; off > 0; off >>= 1)
                m = fminf(m, __shfl_xor(m, off));
            if ((tid & 63) == 0) waveMin[tid >> 6] = m;
        }
        __syncthreads();

        // ---- phase 1b: prune + branch-free dedup + ballot compaction ----
        bool keep = false;
        int  pre  = 0;
        if (tid < C) {
            // 2*r + 1 = 2*70.8837 + 1 = 142.77; 143.5 adds exact-safe slack
            const float thr = fminf(waveMin[0], waveMin[1]) + 143.5f;
            const float2 me = cls[tid];
            unsigned dup = 0u;
#pragma unroll 8
            for (int j = 0; j < C; ++j) {  // LDS broadcasts, no early break
                const float2 o = cls[j];
                dup |= (unsigned)(j < tid) & (unsigned)(o.x == me.x)
                                           & (unsigned)(o.y == me.y);
            }
            keep = (dcen <= thr) && !dup;
            const unsigned long long mask = __ballot(keep);
            const int lane = tid & 63;
            pre = __popcll(mask & ((1ull << lane) - 1ull));
            if (lane == 0) waveCnt[tid >> 6] = __popcll(mask);
        }
        __syncthreads();
        if (keep) {
            const int pos = pre + ((tid >= 64) ? waveCnt[0] : 0);
            cand[pos]    = cls[tid];
            candIdx[pos] = tid;
        }
        __syncthreads();

        const int nCand = waveCnt[0] + waveCnt[1];   // >= 1 (nearest always kept)

        // ---- phase 2 + epilogue, per row-group ----
#pragma unroll
        for (int g = 0; g < GROUPS; ++g) {
            const float fr = frg[g];
            float best[4];
            int   bi[4];
#pragma unroll
            for (int p = 0; p < 4; ++p) { best[p] = FLT_MAX; bi[p] = 0; }

            for (int k = 0; k < nCand; ++k) {
                const float2 cl = cand[k];            // LDS broadcast
                const int    ci = candIdx[k];
                const float  dx  = fr - cl.x;
                const float  dx2 = dx * dx;           // row-constant, reused x4
#pragma unroll
                for (int p = 0; p < 4; ++p) {
                    const float dy  = (cf0 + (float)p) - cl.y;
                    const float d2  = fmaf(dy, dy, dx2);
                    const float key = fmaxf(d2, 1.0f);  // clamp before compare
                    const bool  lt  = key < best[p];    // strict <: first-index ties
                    bi[p]   = lt ? ci  : bi[p];
                    best[p] = lt ? key : best[p];
                }
            }

#pragma unroll
            for (int p = 0; p < 4; ++p) {
                const float bd  = fmaxf(1.0f, sqrtf(best[p]));  // = max(1,sqrt(d2))
                const float wgt = hval[g][p] / bd;
                float v0 = fr * wgt;
                float v1 = (cf0 + (float)p) * wgt;
                const int b0 = __shfl(bi[p], 0);
                if (__ballot(bi[p] == b0) == 0xFFFFFFFFFFFFFFFFull) {
#pragma unroll
                    for (int off = 32; off > 0; off >>= 1) {
                        v0 += __shfl_xor(v0, off);
                        v1 += __shfl_xor(v1, off);
                    }
                    if ((tid & 63) == 0) {
                        unsafeAtomicAdd(&acc[2 * b0 + 0], v0);
                        unsafeAtomicAdd(&acc[2 * b0 + 1], v1);
                    }
                } else {
                    unsafeAtomicAdd(&acc[2 * bi[p] + 0], v0);
                    unsafeAtomicAdd(&acc[2 * bi[p] + 1], v1);
                }
            }
        }
        __syncthreads();

        // ---- publish: device-coherent atomicAdd of NONZERO slots only ----
        // (contributions >= +0.0 and A pre-zeroed -> skipping +0.0 is exact;
        //  typically ~2-24 adds per block, shard depth <= 32)
        float* As = A + ((size_t)it * ASH + (blk & (ASH - 1))) * SLOTS;
        const float a = acc[tid];
        if (a != 0.0f) unsafeAtomicAdd(&As[tid], a);
        __syncthreads();                  // vmcnt drain: RMWs complete at LLC
        if (tid == 0)
            __hip_atomic_fetch_add(&cnt[it * CNT_SH + (blk & (CNT_SH - 1))], 1u,
                                   __ATOMIC_RELAXED, __HIP_MEMORY_SCOPE_AGENT);

        if (it == N_ITER - 1) break;      // handled in finalize below

        // ---- arrival barrier: wave 0 polls shard counters (relaxed) ----
        if (tid < 64) {
            const unsigned* cb = cnt + it * CNT_SH;
            int total = 0;
            do {
                unsigned v = (tid < CNT_SH)
                    ? __hip_atomic_load(&cb[tid], __ATOMIC_RELAXED,
                                        __HIP_MEMORY_SCOPE_AGENT) : 0u;
                int s = (int)v;
#pragma unroll
                for (int off = 32; off > 0; off >>= 1) s += __shfl_xor(s, off);
                total = s;
                if (total < NBLK) __builtin_amdgcn_s_sleep(2);
            } while (total < NBLK);
        }
        __syncthreads();

        // ---- new cluster coords: 4 coherent loads (shard sum), no fence ----
        const float* Ab = A + (size_t)it * ASH * SLOTS + tid;
        float s = 0.0f;
#pragma unroll
        for (int sh = 0; sh < ASH; ++sh)
            s += __hip_atomic_load(Ab + sh * SLOTS, __ATOMIC_RELAXED,
                                   __HIP_MEMORY_SCOPE_AGENT);
        coord = s;
    }

    // ---- finalize: block 0 sums the last iteration's shards into d_out ----
    if (blk == 0) {
        if (tid < 64) {
            const unsigned* cb = cnt + (N_ITER - 1) * CNT_SH;
            int total = 0;
            do {
                unsigned v = (tid < CNT_SH)
                    ? __hip_atomic_load(&cb[tid], __ATOMIC_RELAXED,
                                        __HIP_MEMORY_SCOPE_AGENT) : 0u;
                int s = (int)v;
#pragma unroll
                for (int off = 32; off > 0; off >>= 1) s += __shfl_xor(s, off);
                total = s;
                if (total < NBLK) __builtin_amdgcn_s_sleep(2);
            } while (total < NBLK);
        }
        __syncthreads();

        const float* Ab = A + (size_t)(N_ITER - 1) * ASH * SLOTS + tid;
        float s = 0.0f;
#pragma unroll
        for (int sh = 0; sh < ASH; ++sh)
            s += __hip_atomic_load(Ab + sh * SLOTS, __ATOMIC_RELAXED,
                                   __HIP_MEMORY_SCOPE_AGENT);
        out[tid] = s;
    }
}

extern "C" void kernel_launch(void* const* d_in, const int* in_sizes, int n_in,
                              void* d_out, int out_size, void* d_ws, size_t ws_size,
                              hipStream_t stream) {
    const float* clusters = (const float*)d_in[0];  // [C,2] = 256 floats
    const float* heatmap  = (const float*)d_in[1];  // [H,W] = 1M floats
    float* out = (float*)d_out;                     // [C,2] = 256 floats

    // d_ws layout: A = 8*4*256 floats (32 KB), then counters (512 B)
    float*    A   = (float*)d_ws;
    unsigned* cnt = (unsigned*)(A + (size_t)N_ITER * ASH * SLOTS);

    // zero A and counters (harness re-poisons d_ws before every launch)
    hipMemsetAsync(A, 0,
                   (size_t)N_ITER * ASH * SLOTS * sizeof(float)
                   + N_ITER * CNT_SH * sizeof(unsigned), stream);

    kmeans_persist<<<NBLK, TPB, 0, stream>>>(clusters, heatmap, A, cnt, out);
}

// Round 9
// 238.176 us; speedup vs baseline: 3.6104x; 1.0343x over previous
//
#include <hip/hip_runtime.h>
#include <float.h>

// Problem constants (match reference)
constexpr int H = 1024, W = 1024, C = 128, N_ITER = 8;
constexpr int TPB    = 256;       // threads per block (4 waves)
constexpr int NBLK   = 128;       // 16x8 grid of 64x128 tiles; co-resident by capacity
constexpr int SLOTS  = 2 * C;     // 256 accumulator slots
constexpr int ASH    = 4;         // accumulator shards (RMW depth <= NBLK/ASH = 32)
constexpr int CNT_SH = 16;        // arrival counter shards
constexpr int QUOTA  = NBLK / CNT_SH;   // 8 arrivals per shard
constexpr int LINE_W = 16;        // u32 words per 64-B cache line (padding stride)
constexpr int GROUPS = 8;         // 8 row-groups x 4 cols = 32 px/thread

// Round-8 lesson: data transport via LLC-native atomics is fine (compute ~2us/
// iter) but the barrier still cost ~22us/iter. Hypothesis: all 16 arrival
// counters shared ONE 64-B line, and 128 blocks' continuous 16-lane polling
// gathers interleaved with the arrival RMWs on that single line (TCC per-line
// serialization) -> 10x stretch. Round 9 changes ONLY notification topology:
//   - every counter/flag padded to its own 64-B line
//   - hierarchical arrival: shard line (depth 8) -> root line (depth 16)
//     -> flag line (1 store)
//   - polling: ONE lane per block reads the single flag word + s_sleep(4)
// Data path (A shards, cluster re-read, publish) unchanged from round 8
// (proven absmax 0.0 twice).
//
// Algorithm per iteration (identical math to rounds 1-4, absmax 0.0):
//   phase 1: exact triangle prune (keep iff dcen <= dmin + 2r + 1; 64x128
//            tile, r = 70.8837, threshold 143.5 > 142.77) + exact coincident-
//            cluster dedup (strict-'<' argmin -> only lowest index of a
//            coincident set can win; iters 3+ have ~127 clusters at exactly
//            (0,0) from empty segment_sum segments).
//   phase 2: argmin over surviving candidates; heatmap held in registers.
//   epilogue: wave-uniform fast path else per-lane LDS atomics; publish
//            nonzero slots via device-coherent atomicAdd into A[it][blk&3][:].
__global__ __launch_bounds__(TPB, 4) void kmeans_persist(
    const float* __restrict__ clusters0,  // [SLOTS] input clusters
    const float* __restrict__ heatmap,    // [H,W]
    float* __restrict__ A,                // [N_ITER][ASH][SLOTS], zeroed each launch
    unsigned* __restrict__ cnt,           // [N_ITER][CNT_SH] line-padded, zeroed
    unsigned* __restrict__ root,          // [N_ITER] line-padded, zeroed
    unsigned* __restrict__ flag,          // [N_ITER] line-padded, zeroed
    float* __restrict__ out)              // [SLOTS]
{
    __shared__ float2 cls[C];
    __shared__ float2 cand[C];
    __shared__ int    candIdx[C];
    __shared__ float  waveMin[2];
    __shared__ int    waveCnt[2];
    __shared__ float  acc[SLOTS];         // SLOTS == 256 == TPB

    const int tid = threadIdx.x;
    const int blk = blockIdx.x;
    const int tr  = (blk >> 3) * 64;      // 16 tile-rows
    const int tc  = (blk & 7) * 128;      // 8 tile-cols

    // ---- persistent per-thread pixel state (held for all 8 iterations) ----
    const int   rIn = tid >> 5;           // 0..7
    const int   c0  = tc + (tid & 31) * 4;
    const float cf0 = (float)c0;
    float hval[GROUPS][4];
    float frg[GROUPS];
#pragma unroll
    for (int g = 0; g < GROUPS; ++g) {
        const int row = tr + rIn + 8 * g;
        const float4 h4 = *(const float4*)(heatmap + (size_t)row * W + c0);
        hval[g][0] = h4.x; hval[g][1] = h4.y; hval[g][2] = h4.z; hval[g][3] = h4.w;
        frg[g] = (float)row;
    }
    const float ctrR = (float)tr + 31.5f;
    const float ctrC = (float)tc + 63.5f;

    float coord = clusters0[tid];         // iter-0 cluster coords

    for (int it = 0; it < N_ITER; ++it) {
        // ---- load clusters into LDS ----
        ((float*)cls)[tid] = coord;
        acc[tid] = 0.0f;
        __syncthreads();

        // ---- phase 1a: distance from tile center, per-wave min ----
        float dcen = 0.0f;
        if (tid < C) {
            const float2 cl = cls[tid];
            const float dxr = cl.x - ctrR;
            const float dyc = cl.y - ctrC;
            dcen = sqrtf(dxr * dxr + dyc * dyc);
            float m = dcen;
#pragma unroll
            for (int off = 32; off > 0; off >>= 1)
                m = fminf(m, __shfl_xor(m, off));
            if ((tid & 63) == 0) waveMin[tid >> 6] = m;
        }
        __syncthreads();

        // ---- phase 1b: prune + branch-free dedup + ballot compaction ----
        bool keep = false;
        int  pre  = 0;
        if (tid < C) {
            // 2*r + 1 = 2*70.8837 + 1 = 142.77; 143.5 adds exact-safe slack
            const float thr = fminf(waveMin[0], waveMin[1]) + 143.5f;
            const float2 me = cls[tid];
            unsigned dup = 0u;
#pragma unroll 8
            for (int j = 0; j < C; ++j) {  // LDS broadcasts, no early break
                const float2 o = cls[j];
                dup |= (unsigned)(j < tid) & (unsigned)(o.x == me.x)
                                           & (unsigned)(o.y == me.y);
            }
            keep = (dcen <= thr) && !dup;
            const unsigned long long mask = __ballot(keep);
            const int lane = tid & 63;
            pre = __popcll(mask & ((1ull << lane) - 1ull));
            if (lane == 0) waveCnt[tid >> 6] = __popcll(mask);
        }
        __syncthreads();
        if (keep) {
            const int pos = pre + ((tid >= 64) ? waveCnt[0] : 0);
            cand[pos]    = cls[tid];
            candIdx[pos] = tid;
        }
        __syncthreads();

        const int nCand = waveCnt[0] + waveCnt[1];   // >= 1 (nearest always kept)

        // ---- phase 2 + epilogue, per row-group ----
#pragma unroll
        for (int g = 0; g < GROUPS; ++g) {
            const float fr = frg[g];
            float best[4];
            int   bi[4];
#pragma unroll
            for (int p = 0; p < 4; ++p) { best[p] = FLT_MAX; bi[p] = 0; }

            for (int k = 0; k < nCand; ++k) {
                const float2 cl = cand[k];            // LDS broadcast
                const int    ci = candIdx[k];
                const float  dx  = fr - cl.x;
                const float  dx2 = dx * dx;           // row-constant, reused x4
#pragma unroll
                for (int p = 0; p < 4; ++p) {
                    const float dy  = (cf0 + (float)p) - cl.y;
                    const float d2  = fmaf(dy, dy, dx2);
                    const float key = fmaxf(d2, 1.0f);  // clamp before compare
                    const bool  lt  = key < best[p];    // strict <: first-index ties
                    bi[p]   = lt ? ci  : bi[p];
                    best[p] = lt ? key : best[p];
                }
            }

#pragma unroll
            for (int p = 0; p < 4; ++p) {
                const float bd  = fmaxf(1.0f, sqrtf(best[p]));  // = max(1,sqrt(d2))
                const float wgt = hval[g][p] / bd;
                float v0 = fr * wgt;
                float v1 = (cf0 + (float)p) * wgt;
                const int b0 = __shfl(bi[p], 0);
                if (__ballot(bi[p] == b0) == 0xFFFFFFFFFFFFFFFFull) {
#pragma unroll
                    for (int off = 32; off > 0; off >>= 1) {
                        v0 += __shfl_xor(v0, off);
                        v1 += __shfl_xor(v1, off);
                    }
                    if ((tid & 63) == 0) {
                        unsafeAtomicAdd(&acc[2 * b0 + 0], v0);
                        unsafeAtomicAdd(&acc[2 * b0 + 1], v1);
                    }
                } else {
                    unsafeAtomicAdd(&acc[2 * bi[p] + 0], v0);
                    unsafeAtomicAdd(&acc[2 * bi[p] + 1], v1);
                }
            }
        }
        __syncthreads();

        // ---- publish: device-coherent atomicAdd of NONZERO slots only ----
        float* As = A + ((size_t)it * ASH + (blk & (ASH - 1))) * SLOTS;
        const float a = acc[tid];
        if (a != 0.0f) unsafeAtomicAdd(&As[tid], a);
        __syncthreads();                  // vmcnt drain: RMWs complete at LLC

        // ---- hierarchical arrival: shard line -> root line -> flag line ----
        if (tid == 0) {
            const unsigned old = __hip_atomic_fetch_add(
                &cnt[(it * CNT_SH + (blk & (CNT_SH - 1))) * LINE_W], 1u,
                __ATOMIC_RELAXED, __HIP_MEMORY_SCOPE_AGENT);
            if (old == QUOTA - 1) {       // this block completed its shard
                const unsigned rold = __hip_atomic_fetch_add(
                    &root[it * LINE_W], 1u,
                    __ATOMIC_RELAXED, __HIP_MEMORY_SCOPE_AGENT);
                if (rold == CNT_SH - 1)   // last shard done -> release everyone
                    __hip_atomic_store(&flag[it * LINE_W], 1u,
                                       __ATOMIC_RELAXED, __HIP_MEMORY_SCOPE_AGENT);
            }
        }

        if (it == N_ITER - 1) break;      // finalize below

        // ---- wait: ONE lane polls the single flag word ----
        if (tid == 0) {
            while (!__hip_atomic_load(&flag[it * LINE_W], __ATOMIC_RELAXED,
                                      __HIP_MEMORY_SCOPE_AGENT))
                __builtin_amdgcn_s_sleep(4);
        }
        __syncthreads();

        // ---- new cluster coords: 4 coherent loads (shard sum) ----
        const float* Ab = A + (size_t)it * ASH * SLOTS + tid;
        float s = 0.0f;
#pragma unroll
        for (int sh = 0; sh < ASH; ++sh)
            s += __hip_atomic_load(Ab + sh * SLOTS, __ATOMIC_RELAXED,
                                   __HIP_MEMORY_SCOPE_AGENT);
        coord = s;
    }

    // ---- finalize: block 0 sums the last iteration's shards into d_out ----
    if (blk == 0) {
        if (tid == 0) {
            while (!__hip_atomic_load(&flag[(N_ITER - 1) * LINE_W], __ATOMIC_RELAXED,
                                      __HIP_MEMORY_SCOPE_AGENT))
                __builtin_amdgcn_s_sleep(4);
        }
        __syncthreads();

        const float* Ab = A + (size_t)(N_ITER - 1) * ASH * SLOTS + tid;
        float s = 0.0f;
#pragma unroll
        for (int sh = 0; sh < ASH; ++sh)
            s += __hip_atomic_load(Ab + sh * SLOTS, __ATOMIC_RELAXED,
                                   __HIP_MEMORY_SCOPE_AGENT);
        out[tid] = s;
    }
}

extern "C" void kernel_launch(void* const* d_in, const int* in_sizes, int n_in,
                              void* d_out, int out_size, void* d_ws, size_t ws_size,
                              hipStream_t stream) {
    const float* clusters = (const float*)d_in[0];  // [C,2] = 256 floats
    const float* heatmap  = (const float*)d_in[1];  // [H,W] = 1M floats
    float* out = (float*)d_out;                     // [C,2] = 256 floats

    // d_ws layout (all contiguous, one memset):
    //   A    : 8*4*256 floats          = 32 KB
    //   cnt  : 8*16 lines (64 B each)  =  8 KB
    //   root : 8 lines                 = 512 B
    //   flag : 8 lines                 = 512 B
    float*    A    = (float*)d_ws;
    unsigned* cnt  = (unsigned*)(A + (size_t)N_ITER * ASH * SLOTS);
    unsigned* root = cnt  + N_ITER * CNT_SH * LINE_W;
    unsigned* flag = root + N_ITER * LINE_W;

    const size_t totalBytes =
        (size_t)N_ITER * ASH * SLOTS * sizeof(float)
        + (size_t)N_ITER * (CNT_SH + 2) * LINE_W * sizeof(unsigned);
    hipMemsetAsync(A, 0, totalBytes, stream);

    kmeans_persist<<<NBLK, TPB, 0, stream>>>(clusters, heatmap, A, cnt, root,
                                             flag, out);
}